// Round 1
// baseline (246.058 us; speedup 1.0000x reference)
//
#include <hip/hip_runtime.h>

using f32x4 = __attribute__((ext_vector_type(4))) float;
using f32x2 = __attribute__((ext_vector_type(2))) float;
using s16x8 = __attribute__((ext_vector_type(8))) short;
using u16x4 = __attribute__((ext_vector_type(4))) unsigned short;
using i32x4 = __attribute__((ext_vector_type(4))) int;

#define BB 8
#define NPTS 8192
#define SS 2048
#define D1C 64
#define D2C 256
#define C0K 320
#define MM 65536

__device__ __forceinline__ float b2f(unsigned short h) {
  unsigned int u = ((unsigned int)h) << 16;
  return __builtin_bit_cast(float, u);
}
__device__ __forceinline__ unsigned short f2b(float f) {
  unsigned int u = __builtin_bit_cast(unsigned int, f);
  u += 0x7fffu + ((u >> 16) & 1u);
  return (unsigned short)(u >> 16);
}

// ---------------- cast fp32 weights -> bf16 ----------------
__global__ __launch_bounds__(256) void k_castw(const float* __restrict__ src,
                                               unsigned short* __restrict__ dst, int n) {
  int i4 = (blockIdx.x * 256 + threadIdx.x) * 4;
  if (i4 >= n) return;
  f32x4 v = *(const f32x4*)(src + i4);
  u16x4 o;
#pragma unroll
  for (int j = 0; j < 4; ++j) o[j] = f2b(v[j]);
  *(u16x4*)(dst + i4) = o;
}

// ---------------- transpose points2 [B][256][S] -> f2t [B][S][256] ----------------
__global__ __launch_bounds__(256) void k_tr_f2t(const float* __restrict__ pts2,
                                                float* __restrict__ f2t) {
  __shared__ float tile[64 * 65];
  const int t = threadIdx.x;
  const int s0 = blockIdx.x * 64, c0 = blockIdx.y * 64, b = blockIdx.z;
#pragma unroll
  for (int i = 0; i < 4; ++i) {
    const int cl = i * 16 + (t >> 4);
    const int s4 = (t & 15) * 4;
    f32x4 v = *(const f32x4*)(pts2 + ((size_t)(b * D2C + c0 + cl)) * SS + s0 + s4);
#pragma unroll
    for (int j = 0; j < 4; ++j) tile[cl * 65 + s4 + j] = v[j];
  }
  __syncthreads();
#pragma unroll
  for (int i = 0; i < 4; ++i) {
    const int sl = i * 16 + (t >> 4);
    const int c4 = (t & 15) * 4;
    f32x4 o;
#pragma unroll
    for (int j = 0; j < 4; ++j) o[j] = tile[(c4 + j) * 65 + sl];
    *(f32x4*)(f2t + ((size_t)(b * SS + s0 + sl)) * D2C + c0 + c4) = o;
  }
}

// ---------------- transpose points1 [B][64][N] -> X0 cols 0..63 (bf16) ----------------
__global__ __launch_bounds__(256) void k_tr_x0(const float* __restrict__ pts1,
                                               unsigned short* __restrict__ X0) {
  __shared__ float tile[64 * 65];
  const int t = threadIdx.x;
  const int n0 = blockIdx.x * 64, b = blockIdx.y;
#pragma unroll
  for (int i = 0; i < 4; ++i) {
    const int cl = i * 16 + (t >> 4);
    const int n4 = (t & 15) * 4;
    f32x4 v = *(const f32x4*)(pts1 + ((size_t)(b * D1C + cl)) * NPTS + n0 + n4);
#pragma unroll
    for (int j = 0; j < 4; ++j) tile[cl * 65 + n4 + j] = v[j];
  }
  __syncthreads();
#pragma unroll
  for (int i = 0; i < 4; ++i) {
    const int nl = i * 16 + (t >> 4);
    const int c4 = (t & 15) * 4;
    u16x4 o;
#pragma unroll
    for (int j = 0; j < 4; ++j) o[j] = f2b(tile[(c4 + j) * 65 + nl]);
    *(u16x4*)(X0 + ((size_t)(b * NPTS + n0 + nl)) * C0K + c4) = o;
  }
}

// ---------------- 3-NN + inverse-distance weights ----------------
__global__ __launch_bounds__(256) void k_dist(const float* __restrict__ xyz1,
                                              const float* __restrict__ xyz2,
                                              int* __restrict__ idxb,
                                              float* __restrict__ wb) {
  __shared__ f32x4 p2[SS];
  const int t = threadIdx.x;
  const int b = blockIdx.y;
  const float* xz2 = xyz2 + (size_t)b * 3 * SS;
#pragma unroll
  for (int i = 0; i < 8; ++i) {
    int s = i * 256 + t;
    float x = xz2[s], y = xz2[SS + s], z = xz2[2 * SS + s];
    f32x4 q;
    q[0] = x; q[1] = y; q[2] = z; q[3] = x * x + y * y + z * z;
    p2[s] = q;
  }
  __syncthreads();
  const int n = blockIdx.x * 256 + t;
  const float* xz1 = xyz1 + (size_t)b * 3 * NPTS;
  const float x1 = xz1[n], y1 = xz1[NPTS + n], z1 = xz1[2 * NPTS + n];
  const float r1 = x1 * x1 + y1 * y1 + z1 * z1;
  float dA0 = 1e30f, dA1 = 1e30f, dA2 = 1e30f;
  int iA0 = 0, iA1 = 0, iA2 = 0;
  float dB0 = 1e30f, dB1 = 1e30f, dB2 = 1e30f;
  int iB0 = 0, iB1 = 0, iB2 = 0;
#define INS(dd0, dd1, dd2, ii0, ii1, ii2, d, s)          \
  {                                                      \
    bool c0 = d < dd0, c1 = d < dd1, c2 = d < dd2;       \
    dd2 = c1 ? dd1 : (c2 ? d : dd2);                     \
    ii2 = c1 ? ii1 : (c2 ? s : ii2);                     \
    dd1 = c0 ? dd0 : (c1 ? d : dd1);                     \
    ii1 = c0 ? ii0 : (c1 ? s : ii1);                     \
    dd0 = c0 ? d : dd0;                                  \
    ii0 = c0 ? s : ii0;                                  \
  }
#pragma unroll 4
  for (int s = 0; s < 1024; ++s) {
    f32x4 q = p2[s];
    float d = r1 + q[3] - 2.f * (x1 * q[0] + y1 * q[1] + z1 * q[2]);
    INS(dA0, dA1, dA2, iA0, iA1, iA2, d, s);
    f32x4 q2 = p2[s + 1024];
    float e = r1 + q2[3] - 2.f * (x1 * q2[0] + y1 * q2[1] + z1 * q2[2]);
    int s2 = s + 1024;
    INS(dB0, dB1, dB2, iB0, iB1, iB2, e, s2);
  }
  INS(dA0, dA1, dA2, iA0, iA1, iA2, dB0, iB0);
  INS(dA0, dA1, dA2, iA0, iA1, iA2, dB1, iB1);
  INS(dA0, dA1, dA2, iA0, iA1, iA2, dB2, iB2);
#undef INS
  float w0 = 1.f / (dA0 + 1e-8f), w1 = 1.f / (dA1 + 1e-8f), w2 = 1.f / (dA2 + 1e-8f);
  float inv = 1.f / (w0 + w1 + w2);
  const int p = b * NPTS + n;
  i32x4 iv;
  iv[0] = iA0; iv[1] = iA1; iv[2] = iA2; iv[3] = 0;
  f32x4 wv;
  wv[0] = w0 * inv; wv[1] = w1 * inv; wv[2] = w2 * inv; wv[3] = 0.f;
  *(i32x4*)(idxb + (size_t)p * 4) = iv;
  *(f32x4*)(wb + (size_t)p * 4) = wv;
}

// ---------------- gather+interp -> X0 cols 64..319 (bf16) ----------------
__global__ __launch_bounds__(256) void k_interp(const float* __restrict__ f2t,
                                                const int* __restrict__ idxb,
                                                const float* __restrict__ wb,
                                                unsigned short* __restrict__ X0) {
  const int lane = threadIdx.x & 63, wid = threadIdx.x >> 6;
  const int p = blockIdx.x * 4 + wid;
  const int b = p >> 13;
  i32x4 iv = *(const i32x4*)(idxb + (size_t)p * 4);
  f32x4 wv = *(const f32x4*)(wb + (size_t)p * 4);
  const float* base = f2t + (size_t)b * SS * D2C;
  const int c4 = lane * 4;
  f32x4 a = *(const f32x4*)(base + (size_t)iv[0] * D2C + c4);
  f32x4 c = *(const f32x4*)(base + (size_t)iv[1] * D2C + c4);
  f32x4 e = *(const f32x4*)(base + (size_t)iv[2] * D2C + c4);
  u16x4 o;
#pragma unroll
  for (int j = 0; j < 4; ++j) o[j] = f2b(wv[0] * a[j] + wv[1] * c[j] + wv[2] * e[j]);
  *(u16x4*)(X0 + (size_t)p * C0K + D1C + c4) = o;
}

// ---------------- bf16 MFMA GEMM: C[M][256] = A[M][K] * Bw[256][K]^T + bias ----------------
template <int KDIM, bool TRANSP>
__global__ __launch_bounds__(256) void k_gemm(const unsigned short* __restrict__ A,
                                              const unsigned short* __restrict__ Bw,
                                              const float* __restrict__ bias,
                                              unsigned short* __restrict__ C) {
  __shared__ unsigned short As[128 * 64];
  __shared__ unsigned short Bs[128 * 64];
  const int t = threadIdx.x;
  const int lane = t & 63, wid = t >> 6;
  const int wr = wid >> 1, wc = wid & 1;
  const int m0 = blockIdx.x * 128, n0 = blockIdx.y * 128;
  f32x4 acc[4][4] = {};
  const int rr = t >> 3;          // 0..31: row within 32-row group
  const int kb = (t & 7) * 8;     // k element offset (8 bf16 = 16B)
  for (int k0 = 0; k0 < KDIM; k0 += 64) {
    s16x8 ra[4], rb[4];
#pragma unroll
    for (int i = 0; i < 4; ++i) {
      ra[i] = *(const s16x8*)(A + (size_t)(m0 + i * 32 + rr) * KDIM + k0 + kb);
      rb[i] = *(const s16x8*)(Bw + (size_t)(n0 + i * 32 + rr) * KDIM + k0 + kb);
    }
    __syncthreads();  // previous iteration's LDS reads complete
#pragma unroll
    for (int i = 0; i < 4; ++i) {
      *(s16x8*)&As[(i * 32 + rr) * 64 + kb] = ra[i];
      *(s16x8*)&Bs[(i * 32 + rr) * 64 + kb] = rb[i];
    }
    __syncthreads();
#pragma unroll
    for (int kk = 0; kk < 2; ++kk) {
      const int ko = kk * 32 + (lane >> 4) * 8;
      s16x8 af[4], bf[4];
#pragma unroll
      for (int mi = 0; mi < 4; ++mi)
        af[mi] = *(const s16x8*)&As[(wr * 64 + mi * 16 + (lane & 15)) * 64 + ko];
#pragma unroll
      for (int ni = 0; ni < 4; ++ni)
        bf[ni] = *(const s16x8*)&Bs[(wc * 64 + ni * 16 + (lane & 15)) * 64 + ko];
#pragma unroll
      for (int mi = 0; mi < 4; ++mi)
#pragma unroll
        for (int ni = 0; ni < 4; ++ni)
          acc[mi][ni] =
              __builtin_amdgcn_mfma_f32_16x16x32_bf16(af[mi], bf[ni], acc[mi][ni], 0, 0, 0);
    }
  }
  // epilogue: + bias, store bf16. D frag: col = lane&15 (+16*ni), row = (lane>>4)*4+reg (+16*mi)
  const int cbase = n0 + wc * 64 + (lane & 15);
  float bv[4];
#pragma unroll
  for (int ni = 0; ni < 4; ++ni) bv[ni] = bias[cbase + ni * 16];
  if (!TRANSP) {
#pragma unroll
    for (int mi = 0; mi < 4; ++mi) {
      const size_t rbase = m0 + wr * 64 + mi * 16 + (lane >> 4) * 4;
#pragma unroll
      for (int ni = 0; ni < 4; ++ni) {
        const int cg = cbase + ni * 16;
#pragma unroll
        for (int rj = 0; rj < 4; ++rj)
          C[(rbase + rj) * 256 + cg] = f2b(acc[mi][ni][rj] + bv[ni]);
      }
    }
  } else {
    const size_t bq = m0 >> 13;
    const int nb = (m0 & 8191) + wr * 64 + (lane >> 4) * 4;
#pragma unroll
    for (int mi = 0; mi < 4; ++mi) {
#pragma unroll
      for (int ni = 0; ni < 4; ++ni) {
        const int cg = cbase + ni * 16;
        u16x4 v;
#pragma unroll
        for (int rj = 0; rj < 4; ++rj) v[rj] = f2b(acc[mi][ni][rj] + bv[ni]);
        *(u16x4*)(C + ((bq * 256 + cg) << 13) + nb + mi * 16) = v;
      }
    }
  }
}

// ---------------- BN stats over row-major Y [M][256] bf16 ----------------
__global__ __launch_bounds__(256) void k_stats_rows(const unsigned short* __restrict__ Y,
                                                    float* __restrict__ sums,
                                                    float* __restrict__ ssq) {
  const int c = threadIdx.x;
  const size_t r0 = (size_t)blockIdx.x * 256;
  float s1 = 0.f, s2 = 0.f;
#pragma unroll 8
  for (int j = 0; j < 256; ++j) {
    float v = b2f(Y[(r0 + j) * 256 + c]);
    s1 += v;
    s2 = fmaf(v, v, s2);
  }
  atomicAdd(&sums[c], s1);
  atomicAdd(&ssq[c], s2);
}

// ---------------- BN stats over transposed Yt [B][256][N] bf16 ----------------
__global__ __launch_bounds__(256) void k_stats_t(const unsigned short* __restrict__ Yt,
                                                 float* __restrict__ sums,
                                                 float* __restrict__ ssq) {
  const int t = threadIdx.x;
  const int c = blockIdx.x & 255;
  const size_t base = (size_t)blockIdx.x << 13;
  float s1 = 0.f, s2 = 0.f;
#pragma unroll
  for (int i = 0; i < 8; ++i) {
    u16x4 v4 = *(const u16x4*)(Yt + base + (size_t)(i * 256 + t) * 4);
#pragma unroll
    for (int j = 0; j < 4; ++j) {
      float v = b2f(v4[j]);
      s1 += v;
      s2 = fmaf(v, v, s2);
    }
  }
#pragma unroll
  for (int off = 32; off > 0; off >>= 1) {
    s1 += __shfl_down(s1, off);
    s2 += __shfl_down(s2, off);
  }
  __shared__ float red[8];
  const int lane = t & 63, w = t >> 6;
  if (lane == 0) {
    red[w] = s1;
    red[w + 4] = s2;
  }
  __syncthreads();
  if (t == 0) {
    atomicAdd(&sums[c], red[0] + red[1] + red[2] + red[3]);
    atomicAdd(&ssq[c], red[4] + red[5] + red[6] + red[7]);
  }
}

// ---------------- fold stats + gamma/beta -> per-channel scale/shift ----------------
__global__ void k_params(const float* __restrict__ sums, const float* __restrict__ ssq,
                         const float* __restrict__ gamma, const float* __restrict__ beta,
                         f32x2* __restrict__ P) {
  int c = threadIdx.x;
  float mean = sums[c] * (1.f / 65536.f);
  float var = ssq[c] * (1.f / 65536.f) - mean * mean;
  float sc = gamma[c] * rsqrtf(var + 1e-5f);
  f32x2 pp;
  pp[0] = sc;
  pp[1] = beta[c] - mean * sc;
  P[c] = pp;
}

// ---------------- normalize+relu -> bf16 X1 (row-major) ----------------
__global__ __launch_bounds__(256) void k_norm(const unsigned short* __restrict__ Y,
                                              const f32x2* __restrict__ P,
                                              unsigned short* __restrict__ X) {
  const size_t i4 = ((size_t)blockIdx.x * 256 + threadIdx.x) * 4;
  const int c = (int)(i4 & 255);
  u16x4 y = *(const u16x4*)(Y + i4);
  u16x4 o;
#pragma unroll
  for (int j = 0; j < 4; ++j) {
    f32x2 p = P[c + j];
    o[j] = f2b(fmaxf(fmaf(b2f(y[j]), p[0], p[1]), 0.f));
  }
  *(u16x4*)(X + i4) = o;
}

// ---------------- normalize+relu -> fp32 out (already [B][256][N]) ----------------
__global__ __launch_bounds__(256) void k_final(const unsigned short* __restrict__ Yt,
                                               const f32x2* __restrict__ P,
                                               float* __restrict__ out) {
  const size_t i4 = ((size_t)blockIdx.x * 256 + threadIdx.x) * 4;
  const int c = (int)((i4 >> 13) & 255);
  const f32x2 p = P[c];
  u16x4 y = *(const u16x4*)(Yt + i4);
  f32x4 o;
#pragma unroll
  for (int j = 0; j < 4; ++j) o[j] = fmaxf(fmaf(b2f(y[j]), p[0], p[1]), 0.f);
  *(f32x4*)(out + i4) = o;
}

extern "C" void kernel_launch(void* const* d_in, const int* in_sizes, int n_in,
                              void* d_out, int out_size, void* d_ws, size_t ws_size,
                              hipStream_t stream) {
  const float* xyz1 = (const float*)d_in[0];
  const float* xyz2 = (const float*)d_in[1];
  const float* pts1 = (const float*)d_in[2];
  const float* pts2 = (const float*)d_in[3];
  const float* W0 = (const float*)d_in[4];
  const float* b0 = (const float*)d_in[5];
  const float* g0 = (const float*)d_in[6];
  const float* be0 = (const float*)d_in[7];
  const float* W1 = (const float*)d_in[8];
  const float* b1 = (const float*)d_in[9];
  const float* g1 = (const float*)d_in[10];
  const float* be1 = (const float*)d_in[11];
  float* out = (float*)d_out;
  char* ws = (char*)d_ws;

  // workspace layout (aliased; peak 90.3 MB):
  float* f2t = (float*)(ws + 0);                          // 16 MB, live K1..K4
  int* idxb = (int*)(ws + 16777216);                      // 1 MB,  live K2..K4
  float* wb = (float*)(ws + 17825792);                    // 1 MB,  live K2..K4
  unsigned short* X0 = (unsigned short*)(ws + 18874368);  // 40 MB, live K3..K5
  unsigned short* Y0 = (unsigned short*)(ws + 60817408);  // 32 MB, live K5..K8
  unsigned short* X1 = (unsigned short*)(ws + 0);         // 32 MB, live K8..K9 (aliases f2t/idx/wb/X0-head)
  unsigned short* Yt = (unsigned short*)(ws + 60817408);  // 32 MB, live K9..K12 (aliases Y0)
  unsigned short* W0b = (unsigned short*)(ws + 94371840);
  unsigned short* W1b = (unsigned short*)(ws + 94535680);
  float* sums0 = (float*)(ws + 94666752);
  float* ssq0 = sums0 + 256;
  float* sums1 = sums0 + 512;
  float* ssq1 = sums0 + 768;
  f32x2* P0 = (f32x2*)(ws + 94670848);
  f32x2* P1 = (f32x2*)(ws + 94672896);

  hipMemsetAsync(sums0, 0, 4096, stream);
  k_castw<<<80, 256, 0, stream>>>(W0, W0b, 81920);
  k_castw<<<64, 256, 0, stream>>>(W1, W1b, 65536);
  k_tr_f2t<<<dim3(32, 4, BB), 256, 0, stream>>>(pts2, f2t);
  k_dist<<<dim3(32, BB), 256, 0, stream>>>(xyz1, xyz2, idxb, wb);
  k_tr_x0<<<dim3(128, BB), 256, 0, stream>>>(pts1, X0);
  k_interp<<<16384, 256, 0, stream>>>(f2t, idxb, wb, X0);
  k_gemm<320, false><<<dim3(512, 2), 256, 0, stream>>>(X0, W0b, b0, Y0);
  k_stats_rows<<<256, 256, 0, stream>>>(Y0, sums0, ssq0);
  k_params<<<1, 256, 0, stream>>>(sums0, ssq0, g0, be0, P0);
  k_norm<<<16384, 256, 0, stream>>>(Y0, P0, X1);
  k_gemm<256, true><<<dim3(512, 2), 256, 0, stream>>>(X1, W1b, b1, Yt);
  k_stats_t<<<2048, 256, 0, stream>>>(Yt, sums1, ssq1);
  k_params<<<1, 256, 0, stream>>>(sums1, ssq1, g1, be1, P1);
  k_final<<<16384, 256, 0, stream>>>(Yt, P1, out);
}

// Round 2
// 223.794 us; speedup vs baseline: 1.0995x; 1.0995x over previous
//
#include <hip/hip_runtime.h>

using f32x4 = __attribute__((ext_vector_type(4))) float;
using f32x2 = __attribute__((ext_vector_type(2))) float;
using s16x8 = __attribute__((ext_vector_type(8))) short;
using u16x4 = __attribute__((ext_vector_type(4))) unsigned short;
using i32x4 = __attribute__((ext_vector_type(4))) int;

#define BB 8
#define NPTS 8192
#define SS 2048
#define D1C 64
#define D2C 256
#define C0K 320
#define MM 65536
#define SCHUNKS 4
#define SCH (SS / SCHUNKS)  // 512

__device__ __forceinline__ float b2f(unsigned short h) {
  unsigned int u = ((unsigned int)h) << 16;
  return __builtin_bit_cast(float, u);
}
__device__ __forceinline__ unsigned short f2b(float f) {
  unsigned int u = __builtin_bit_cast(unsigned int, f);
  u += 0x7fffu + ((u >> 16) & 1u);
  return (unsigned short)(u >> 16);
}

// top-3 insert: distances via med3/min (3 VALU), indices via cmp+cndmask (strict < => stable)
__device__ __forceinline__ void ins3(float& dd0, float& dd1, float& dd2, int& ii0, int& ii1,
                                     int& ii2, float d, int s) {
  bool c0 = d < dd0, c1 = d < dd1, c2 = d < dd2;
  ii2 = c1 ? ii1 : (c2 ? s : ii2);
  ii1 = c0 ? ii0 : (c1 ? s : ii1);
  ii0 = c0 ? s : ii0;
  dd2 = __builtin_amdgcn_fmed3f(dd1, dd2, d);
  dd1 = __builtin_amdgcn_fmed3f(dd0, dd1, d);
  dd0 = fminf(dd0, d);
}

// ---------------- cast fp32 weights -> bf16 ----------------
__global__ __launch_bounds__(256) void k_castw(const float* __restrict__ src,
                                               unsigned short* __restrict__ dst, int n) {
  int i4 = (blockIdx.x * 256 + threadIdx.x) * 4;
  if (i4 >= n) return;
  f32x4 v = *(const f32x4*)(src + i4);
  u16x4 o;
#pragma unroll
  for (int j = 0; j < 4; ++j) o[j] = f2b(v[j]);
  *(u16x4*)(dst + i4) = o;
}

// ---------------- transpose points2 [B][256][S] -> f2t [B][S][256] ----------------
__global__ __launch_bounds__(256) void k_tr_f2t(const float* __restrict__ pts2,
                                                float* __restrict__ f2t) {
  __shared__ float tile[64 * 65];
  const int t = threadIdx.x;
  const int s0 = blockIdx.x * 64, c0 = blockIdx.y * 64, b = blockIdx.z;
#pragma unroll
  for (int i = 0; i < 4; ++i) {
    const int cl = i * 16 + (t >> 4);
    const int s4 = (t & 15) * 4;
    f32x4 v = *(const f32x4*)(pts2 + ((size_t)(b * D2C + c0 + cl)) * SS + s0 + s4);
#pragma unroll
    for (int j = 0; j < 4; ++j) tile[cl * 65 + s4 + j] = v[j];
  }
  __syncthreads();
#pragma unroll
  for (int i = 0; i < 4; ++i) {
    const int sl = i * 16 + (t >> 4);
    const int c4 = (t & 15) * 4;
    f32x4 o;
#pragma unroll
    for (int j = 0; j < 4; ++j) o[j] = tile[(c4 + j) * 65 + sl];
    *(f32x4*)(f2t + ((size_t)(b * SS + s0 + sl)) * D2C + c0 + c4) = o;
  }
}

// ---------------- transpose points1 [B][64][N] -> X0 cols 0..63 (bf16) ----------------
__global__ __launch_bounds__(256) void k_tr_x0(const float* __restrict__ pts1,
                                               unsigned short* __restrict__ X0) {
  __shared__ float tile[64 * 65];
  const int t = threadIdx.x;
  const int n0 = blockIdx.x * 64, b = blockIdx.y;
#pragma unroll
  for (int i = 0; i < 4; ++i) {
    const int cl = i * 16 + (t >> 4);
    const int n4 = (t & 15) * 4;
    f32x4 v = *(const f32x4*)(pts1 + ((size_t)(b * D1C + cl)) * NPTS + n0 + n4);
#pragma unroll
    for (int j = 0; j < 4; ++j) tile[cl * 65 + n4 + j] = v[j];
  }
  __syncthreads();
#pragma unroll
  for (int i = 0; i < 4; ++i) {
    const int nl = i * 16 + (t >> 4);
    const int c4 = (t & 15) * 4;
    u16x4 o;
#pragma unroll
    for (int j = 0; j < 4; ++j) o[j] = f2b(tile[(c4 + j) * 65 + nl]);
    *(u16x4*)(X0 + ((size_t)(b * NPTS + n0 + nl)) * C0K + c4) = o;
  }
}

// ---------------- 3-NN partial: per S-chunk top-3 ----------------
__global__ __launch_bounds__(256) void k_dist(const float* __restrict__ xyz1,
                                              const float* __restrict__ xyz2,
                                              f32x4* __restrict__ pd,
                                              i32x4* __restrict__ pi) {
  __shared__ f32x4 p2[SCH];
  const int t = threadIdx.x;
  const int b = blockIdx.z;
  const int cy = blockIdx.y;
  const int ss0 = cy * SCH;
  const float* xz2 = xyz2 + (size_t)b * 3 * SS;
#pragma unroll
  for (int i = 0; i < SCH / 256; ++i) {
    int s = i * 256 + t;
    float x = xz2[ss0 + s], y = xz2[SS + ss0 + s], z = xz2[2 * SS + ss0 + s];
    f32x4 q;
    q[0] = x; q[1] = y; q[2] = z; q[3] = x * x + y * y + z * z;
    p2[s] = q;
  }
  __syncthreads();
  const int n = blockIdx.x * 256 + t;
  const float* xz1 = xyz1 + (size_t)b * 3 * NPTS;
  const float x1 = xz1[n], y1 = xz1[NPTS + n], z1 = xz1[2 * NPTS + n];
  const float r1 = x1 * x1 + y1 * y1 + z1 * z1;
  float dA0 = 1e30f, dA1 = 1e30f, dA2 = 1e30f;
  int iA0 = 0, iA1 = 0, iA2 = 0;
  float dB0 = 1e30f, dB1 = 1e30f, dB2 = 1e30f;
  int iB0 = 0, iB1 = 0, iB2 = 0;
#pragma unroll 8
  for (int s = 0; s < SCH / 2; ++s) {
    f32x4 q = p2[s];
    float d = r1 + q[3] - 2.f * (x1 * q[0] + y1 * q[1] + z1 * q[2]);
    ins3(dA0, dA1, dA2, iA0, iA1, iA2, d, ss0 + s);
    f32x4 q2 = p2[s + SCH / 2];
    float e = r1 + q2[3] - 2.f * (x1 * q2[0] + y1 * q2[1] + z1 * q2[2]);
    ins3(dB0, dB1, dB2, iB0, iB1, iB2, e, ss0 + SCH / 2 + s);
  }
  // fold B chain into A (B indices all larger -> strict < keeps stability)
  ins3(dA0, dA1, dA2, iA0, iA1, iA2, dB0, iB0);
  ins3(dA0, dA1, dA2, iA0, iA1, iA2, dB1, iB1);
  ins3(dA0, dA1, dA2, iA0, iA1, iA2, dB2, iB2);
  const size_t p = ((size_t)(b * SCHUNKS + cy)) * NPTS + n;
  f32x4 dv;
  dv[0] = dA0; dv[1] = dA1; dv[2] = dA2; dv[3] = 0.f;
  i32x4 iv;
  iv[0] = iA0; iv[1] = iA1; iv[2] = iA2; iv[3] = 0;
  pd[p] = dv;
  pi[p] = iv;
}

// ---------------- merge 4 partial top-3 -> final idx + weights ----------------
__global__ __launch_bounds__(256) void k_merge(const f32x4* __restrict__ pd,
                                               const i32x4* __restrict__ pi,
                                               int* __restrict__ idxb,
                                               float* __restrict__ wb) {
  const int p = blockIdx.x * 256 + threadIdx.x;
  const int b = p >> 13, n = p & 8191;
  const size_t base = ((size_t)(b * SCHUNKS)) * NPTS + n;
  f32x4 dv = pd[base];
  i32x4 ivv = pi[base];
  float d0 = dv[0], d1 = dv[1], d2 = dv[2];
  int i0 = ivv[0], i1 = ivv[1], i2 = ivv[2];
#pragma unroll
  for (int c = 1; c < SCHUNKS; ++c) {
    f32x4 dc = pd[base + (size_t)c * NPTS];
    i32x4 ic = pi[base + (size_t)c * NPTS];
    ins3(d0, d1, d2, i0, i1, i2, dc[0], ic[0]);
    ins3(d0, d1, d2, i0, i1, i2, dc[1], ic[1]);
    ins3(d0, d1, d2, i0, i1, i2, dc[2], ic[2]);
  }
  float w0 = 1.f / (d0 + 1e-8f), w1 = 1.f / (d1 + 1e-8f), w2 = 1.f / (d2 + 1e-8f);
  float inv = 1.f / (w0 + w1 + w2);
  i32x4 iv;
  iv[0] = i0; iv[1] = i1; iv[2] = i2; iv[3] = 0;
  f32x4 wv;
  wv[0] = w0 * inv; wv[1] = w1 * inv; wv[2] = w2 * inv; wv[3] = 0.f;
  *(i32x4*)(idxb + (size_t)p * 4) = iv;
  *(f32x4*)(wb + (size_t)p * 4) = wv;
}

// ---------------- gather+interp -> X0 cols 64..319 (bf16) ----------------
__global__ __launch_bounds__(256) void k_interp(const float* __restrict__ f2t,
                                                const int* __restrict__ idxb,
                                                const float* __restrict__ wb,
                                                unsigned short* __restrict__ X0) {
  const int lane = threadIdx.x & 63, wid = threadIdx.x >> 6;
  const int p = blockIdx.x * 4 + wid;
  const int b = p >> 13;
  i32x4 iv = *(const i32x4*)(idxb + (size_t)p * 4);
  f32x4 wv = *(const f32x4*)(wb + (size_t)p * 4);
  const float* base = f2t + (size_t)b * SS * D2C;
  const int c4 = lane * 4;
  f32x4 a = *(const f32x4*)(base + (size_t)iv[0] * D2C + c4);
  f32x4 c = *(const f32x4*)(base + (size_t)iv[1] * D2C + c4);
  f32x4 e = *(const f32x4*)(base + (size_t)iv[2] * D2C + c4);
  u16x4 o;
#pragma unroll
  for (int j = 0; j < 4; ++j) o[j] = f2b(wv[0] * a[j] + wv[1] * c[j] + wv[2] * e[j]);
  *(u16x4*)(X0 + (size_t)p * C0K + D1C + c4) = o;
}

// ---------------- bf16 MFMA GEMM: C[M][256] = A[M][K] * Bw[256][K]^T + bias ----------------
template <int KDIM, bool TRANSP>
__global__ __launch_bounds__(256) void k_gemm(const unsigned short* __restrict__ A,
                                              const unsigned short* __restrict__ Bw,
                                              const float* __restrict__ bias,
                                              unsigned short* __restrict__ C) {
  __shared__ unsigned short As[128 * 64];
  __shared__ unsigned short Bs[128 * 64];
  const int t = threadIdx.x;
  const int lane = t & 63, wid = t >> 6;
  const int wr = wid >> 1, wc = wid & 1;
  const int m0 = blockIdx.x * 128, n0 = blockIdx.y * 128;
  f32x4 acc[4][4] = {};
  const int rr = t >> 3;          // 0..31: row within 32-row group
  const int kb = (t & 7) * 8;     // k element offset (8 bf16 = 16B)
  for (int k0 = 0; k0 < KDIM; k0 += 64) {
    s16x8 ra[4], rb[4];
#pragma unroll
    for (int i = 0; i < 4; ++i) {
      ra[i] = *(const s16x8*)(A + (size_t)(m0 + i * 32 + rr) * KDIM + k0 + kb);
      rb[i] = *(const s16x8*)(Bw + (size_t)(n0 + i * 32 + rr) * KDIM + k0 + kb);
    }
    __syncthreads();  // previous iteration's LDS reads complete
#pragma unroll
    for (int i = 0; i < 4; ++i) {
      *(s16x8*)&As[(i * 32 + rr) * 64 + kb] = ra[i];
      *(s16x8*)&Bs[(i * 32 + rr) * 64 + kb] = rb[i];
    }
    __syncthreads();
#pragma unroll
    for (int kk = 0; kk < 2; ++kk) {
      const int ko = kk * 32 + (lane >> 4) * 8;
      s16x8 af[4], bf[4];
#pragma unroll
      for (int mi = 0; mi < 4; ++mi)
        af[mi] = *(const s16x8*)&As[(wr * 64 + mi * 16 + (lane & 15)) * 64 + ko];
#pragma unroll
      for (int ni = 0; ni < 4; ++ni)
        bf[ni] = *(const s16x8*)&Bs[(wc * 64 + ni * 16 + (lane & 15)) * 64 + ko];
#pragma unroll
      for (int mi = 0; mi < 4; ++mi)
#pragma unroll
        for (int ni = 0; ni < 4; ++ni)
          acc[mi][ni] =
              __builtin_amdgcn_mfma_f32_16x16x32_bf16(af[mi], bf[ni], acc[mi][ni], 0, 0, 0);
    }
  }
  // epilogue: + bias, store bf16. D frag: col = lane&15 (+16*ni), row = (lane>>4)*4+reg (+16*mi)
  const int cbase = n0 + wc * 64 + (lane & 15);
  float bv[4];
#pragma unroll
  for (int ni = 0; ni < 4; ++ni) bv[ni] = bias[cbase + ni * 16];
  if (!TRANSP) {
#pragma unroll
    for (int mi = 0; mi < 4; ++mi) {
      const size_t rbase = m0 + wr * 64 + mi * 16 + (lane >> 4) * 4;
#pragma unroll
      for (int ni = 0; ni < 4; ++ni) {
        const int cg = cbase + ni * 16;
#pragma unroll
        for (int rj = 0; rj < 4; ++rj)
          C[(rbase + rj) * 256 + cg] = f2b(acc[mi][ni][rj] + bv[ni]);
      }
    }
  } else {
    const size_t bq = m0 >> 13;
    const int nb = (m0 & 8191) + wr * 64 + (lane >> 4) * 4;
#pragma unroll
    for (int mi = 0; mi < 4; ++mi) {
#pragma unroll
      for (int ni = 0; ni < 4; ++ni) {
        const int cg = cbase + ni * 16;
        u16x4 v;
#pragma unroll
        for (int rj = 0; rj < 4; ++rj) v[rj] = f2b(acc[mi][ni][rj] + bv[ni]);
        *(u16x4*)(C + ((bq * 256 + cg) << 13) + nb + mi * 16) = v;
      }
    }
  }
}

// ---------------- BN stats over row-major Y [M][256] bf16 ----------------
__global__ __launch_bounds__(256) void k_stats_rows(const unsigned short* __restrict__ Y,
                                                    float* __restrict__ sums,
                                                    float* __restrict__ ssq) {
  const int c = threadIdx.x;
  const size_t r0 = (size_t)blockIdx.x * 256;
  float s1 = 0.f, s2 = 0.f;
#pragma unroll 8
  for (int j = 0; j < 256; ++j) {
    float v = b2f(Y[(r0 + j) * 256 + c]);
    s1 += v;
    s2 = fmaf(v, v, s2);
  }
  atomicAdd(&sums[c], s1);
  atomicAdd(&ssq[c], s2);
}

// ---------------- BN stats over transposed Yt [B][256][N] bf16 ----------------
__global__ __launch_bounds__(256) void k_stats_t(const unsigned short* __restrict__ Yt,
                                                 float* __restrict__ sums,
                                                 float* __restrict__ ssq) {
  const int t = threadIdx.x;
  const int c = blockIdx.x & 255;
  const size_t base = (size_t)blockIdx.x << 13;
  float s1 = 0.f, s2 = 0.f;
#pragma unroll
  for (int i = 0; i < 8; ++i) {
    u16x4 v4 = *(const u16x4*)(Yt + base + (size_t)(i * 256 + t) * 4);
#pragma unroll
    for (int j = 0; j < 4; ++j) {
      float v = b2f(v4[j]);
      s1 += v;
      s2 = fmaf(v, v, s2);
    }
  }
#pragma unroll
  for (int off = 32; off > 0; off >>= 1) {
    s1 += __shfl_down(s1, off);
    s2 += __shfl_down(s2, off);
  }
  __shared__ float red[8];
  const int lane = t & 63, w = t >> 6;
  if (lane == 0) {
    red[w] = s1;
    red[w + 4] = s2;
  }
  __syncthreads();
  if (t == 0) {
    atomicAdd(&sums[c], red[0] + red[1] + red[2] + red[3]);
    atomicAdd(&ssq[c], red[4] + red[5] + red[6] + red[7]);
  }
}

// ---------------- fold stats + gamma/beta -> per-channel scale/shift ----------------
__global__ void k_params(const float* __restrict__ sums, const float* __restrict__ ssq,
                         const float* __restrict__ gamma, const float* __restrict__ beta,
                         f32x2* __restrict__ P) {
  int c = threadIdx.x;
  float mean = sums[c] * (1.f / 65536.f);
  float var = ssq[c] * (1.f / 65536.f) - mean * mean;
  float sc = gamma[c] * rsqrtf(var + 1e-5f);
  f32x2 pp;
  pp[0] = sc;
  pp[1] = beta[c] - mean * sc;
  P[c] = pp;
}

// ---------------- normalize+relu -> bf16 X1 (row-major) ----------------
__global__ __launch_bounds__(256) void k_norm(const unsigned short* __restrict__ Y,
                                              const f32x2* __restrict__ P,
                                              unsigned short* __restrict__ X) {
  const size_t i4 = ((size_t)blockIdx.x * 256 + threadIdx.x) * 4;
  const int c = (int)(i4 & 255);
  u16x4 y = *(const u16x4*)(Y + i4);
  u16x4 o;
#pragma unroll
  for (int j = 0; j < 4; ++j) {
    f32x2 p = P[c + j];
    o[j] = f2b(fmaxf(fmaf(b2f(y[j]), p[0], p[1]), 0.f));
  }
  *(u16x4*)(X + i4) = o;
}

// ---------------- normalize+relu -> fp32 out (already [B][256][N]) ----------------
__global__ __launch_bounds__(256) void k_final(const unsigned short* __restrict__ Yt,
                                               const f32x2* __restrict__ P,
                                               float* __restrict__ out) {
  const size_t i4 = ((size_t)blockIdx.x * 256 + threadIdx.x) * 4;
  const int c = (int)((i4 >> 13) & 255);
  const f32x2 p = P[c];
  u16x4 y = *(const u16x4*)(Yt + i4);
  f32x4 o;
#pragma unroll
  for (int j = 0; j < 4; ++j) o[j] = fmaxf(fmaf(b2f(y[j]), p[0], p[1]), 0.f);
  *(f32x4*)(out + i4) = o;
}

extern "C" void kernel_launch(void* const* d_in, const int* in_sizes, int n_in,
                              void* d_out, int out_size, void* d_ws, size_t ws_size,
                              hipStream_t stream) {
  const float* xyz1 = (const float*)d_in[0];
  const float* xyz2 = (const float*)d_in[1];
  const float* pts1 = (const float*)d_in[2];
  const float* pts2 = (const float*)d_in[3];
  const float* W0 = (const float*)d_in[4];
  const float* b0 = (const float*)d_in[5];
  const float* g0 = (const float*)d_in[6];
  const float* be0 = (const float*)d_in[7];
  const float* W1 = (const float*)d_in[8];
  const float* b1 = (const float*)d_in[9];
  const float* g1 = (const float*)d_in[10];
  const float* be1 = (const float*)d_in[11];
  float* out = (float*)d_out;
  char* ws = (char*)d_ws;

  // workspace layout (aliased; peak ~90.3 MB):
  float* f2t = (float*)(ws + 0);                          // 16 MB, live K1..K4
  int* idxb = (int*)(ws + 16777216);                      // 1 MB,  live merge..interp
  float* wb = (float*)(ws + 17825792);                    // 1 MB,  live merge..interp
  unsigned short* X0 = (unsigned short*)(ws + 18874368);  // 40 MB, live tr_x0..gemm0
  unsigned short* Y0 = (unsigned short*)(ws + 60817408);  // 32 MB, live gemm0..norm
  unsigned short* X1 = (unsigned short*)(ws + 0);         // 32 MB, live norm..gemm1
  unsigned short* Yt = (unsigned short*)(ws + 60817408);  // 32 MB, live gemm1..final
  f32x4* pd = (f32x4*)(ws + 60817408);                    // 4 MB,  live dist..merge (aliases Y0)
  i32x4* pi = (i32x4*)(ws + 65011712);                    // 4 MB,  live dist..merge
  unsigned short* W0b = (unsigned short*)(ws + 94371840);
  unsigned short* W1b = (unsigned short*)(ws + 94535680);
  float* sums0 = (float*)(ws + 94666752);
  float* ssq0 = sums0 + 256;
  float* sums1 = sums0 + 512;
  float* ssq1 = sums0 + 768;
  f32x2* P0 = (f32x2*)(ws + 94670848);
  f32x2* P1 = (f32x2*)(ws + 94672896);

  hipMemsetAsync(sums0, 0, 4096, stream);
  k_castw<<<80, 256, 0, stream>>>(W0, W0b, 81920);
  k_castw<<<64, 256, 0, stream>>>(W1, W1b, 65536);
  k_tr_f2t<<<dim3(32, 4, BB), 256, 0, stream>>>(pts2, f2t);
  k_dist<<<dim3(32, SCHUNKS, BB), 256, 0, stream>>>(xyz1, xyz2, pd, pi);
  k_merge<<<256, 256, 0, stream>>>(pd, pi, idxb, wb);
  k_tr_x0<<<dim3(128, BB), 256, 0, stream>>>(pts1, X0);
  k_interp<<<16384, 256, 0, stream>>>(f2t, idxb, wb, X0);
  k_gemm<320, false><<<dim3(512, 2), 256, 0, stream>>>(X0, W0b, b0, Y0);
  k_stats_rows<<<256, 256, 0, stream>>>(Y0, sums0, ssq0);
  k_params<<<1, 256, 0, stream>>>(sums0, ssq0, g0, be0, P0);
  k_norm<<<16384, 256, 0, stream>>>(Y0, P0, X1);
  k_gemm<256, true><<<dim3(512, 2), 256, 0, stream>>>(X1, W1b, b1, Yt);
  k_stats_t<<<2048, 256, 0, stream>>>(Yt, sums1, ssq1);
  k_params<<<1, 256, 0, stream>>>(sums1, ssq1, g1, be1, P1);
  k_final<<<16384, 256, 0, stream>>>(Yt, P1, out);
}